// Round 7
// baseline (815.356 us; speedup 1.0000x reference)
//
#include <hip/hip_runtime.h>
#include <hip/hip_bf16.h>

// GRU (reset_after) fused, MI355X gfx950. B=8192, T=256, F=64, H=50.
// 256 blocks x 512 threads; block = 2 independent 16-row groups (A: waves
// 0-3, B: waves 4-7) phase-staggered half a step so every SIMD always has
// one wave doing MFMA/ds work and one doing gate VALU work:
//   phase1: A MFMA-stage(t) | B gate-stage(t-1); barrier;
//   phase2: A gate-stage(t) | B MFMA-stage(t);   barrier.
// Gate-blocked B columns give each lane its full z/r/h gate inputs locally.
// Barriers are raw (lgkmcnt-only): x prefetch loads stay in flight.

typedef __attribute__((ext_vector_type(8))) short s16x8;
typedef __attribute__((ext_vector_type(4))) short s16x4;
typedef __attribute__((ext_vector_type(4))) float f32x4;

#define TS 256

__device__ __forceinline__ unsigned short f2bf(float f) {
  return __builtin_bit_cast(unsigned short, __float2bfloat16(f));
}

#define RAWBAR()                                                \
  do {                                                          \
    asm volatile("s_waitcnt lgkmcnt(0)" ::: "memory");          \
    __builtin_amdgcn_sched_barrier(0);                          \
    __builtin_amdgcn_s_barrier();                               \
  } while (0)

__global__ __launch_bounds__(512, 1) void gru_fused(
    const float* __restrict__ x,  const float* __restrict__ W,
    const float* __restrict__ U,  const float* __restrict__ b,
    const float* __restrict__ Wd, const float* __restrict__ bdp,
    float* __restrict__ out)
{
  __shared__ __align__(16) unsigned short xbuf[2][2][2][512]; // [grp][par][kc]
  __shared__ __align__(16) unsigned short hbuf[2][2][2][512];
  __shared__ float red[2][4][16];

  const int tid = threadIdx.x;
  const int l   = tid & 63;
  const int w   = tid >> 6;      // 0..7
  const int grp = w >> 2;        // 0 = group A, 1 = group B
  const int wg  = w & 3;         // wave within group
  const int lhi = l >> 4, llo = l & 15;
  const int row0 = (blockIdx.x << 5) + (grp << 4);
  const int u = (wg << 4) + llo; // this thread's hidden unit (pad >= 50)

  // zero all hbuf (par0 needed: h(t=0)=0; pad stays harmless)
  ((unsigned long long*)hbuf)[tid]       = 0ULL;
  ((unsigned long long*)hbuf)[tid + 512] = 0ULL;

  float bz = 0.f, br = 0.f, bh0 = 0.f, bh1 = 0.f;
  if (u < 50) {
    bz  = b[u]       + b[150 + u];
    br  = b[50 + u]  + b[200 + u];
    bh0 = b[100 + u];
    bh1 = b[250 + u];
  }

  // B fragments, gate-blocked columns: g in {z,r,h} -> source col g*50+u.
  s16x8 breg[3][4];
  #pragma unroll
  for (int g = 0; g < 3; ++g) {
    #pragma unroll
    for (int kc = 0; kc < 4; ++kc) {
      s16x8 f;
      #pragma unroll
      for (int i = 0; i < 8; ++i) {
        const int k = kc * 32 + lhi * 8 + i;
        float v = 0.f;
        if (u < 50 && k < 114)
          v = (k < 64) ? W[k * 150 + g * 50 + u]
                       : U[(k - 64) * 150 + g * 50 + u];
        f[i] = (short)f2bf(v);
      }
      breg[g][kc] = f;
    }
  }

  // per-group balanced x staging (256 threads/group)
  const int gt    = tid & 255;
  const int sc    = gt >> 7;
  const int sla   = (gt >> 1) & 63;
  const int shalf = gt & 1;
  const float* xp = x + (long)(row0 + (sla & 15)) * (TS * 64)
                      + sc * 32 + (sla >> 4) * 8 + shalf * 4;
  unsigned short* const xd0 = &xbuf[grp][0][sc][sla * 8 + shalf * 4];
  unsigned short* const xd1 = &xbuf[grp][1][sc][sla * 8 + shalf * 4];
  // ring: reg loaded at iter j is converted at iter j+4.
  // A converts x(T+1) at iter T (lead 5); B converts x(T) at iter T (lead 4).
  const int lead = 5 - grp;

  // prologue: stage x(0) -> xbuf[grp][0]; fill reg ring
  {
    const f32x4 x0 = *(const f32x4*)xp;
    s16x4 pk;
    pk[0] = (short)f2bf(x0[0]); pk[1] = (short)f2bf(x0[1]);
    pk[2] = (short)f2bf(x0[2]); pk[3] = (short)f2bf(x0[3]);
    *(s16x4*)xd0 = pk;
  }
  const float* xq = xp + (long)(1 - grp) * 64;
  f32x4 R0 = *(const f32x4*)(xq);
  f32x4 R1 = *(const f32x4*)(xq + 64);
  f32x4 R2 = *(const f32x4*)(xq + 128);
  f32x4 R3 = *(const f32x4*)(xq + 192);
  f32x4 S0, S1, S2, S3;
  __syncthreads();

  float h0 = 0.f, h1 = 0.f, h2 = 0.f, h3 = 0.f;
  f32x4 lo[3], hi[3];

#define MFMA_STAGE(T, NXT)                                                     \
  {                                                                            \
    int tl = (T) + lead; if (tl > TS - 1) tl = TS - 1;                         \
    NXT = *(const f32x4*)(xp + (long)tl * 64);                                 \
    const int PAR = (T) & 1;                                                   \
    const s16x8 a2 = *(const s16x8*)&hbuf[grp][PAR][0][l * 8];                 \
    const s16x8 a3 = *(const s16x8*)&hbuf[grp][PAR][1][l * 8];                 \
    const s16x8 a0 = *(const s16x8*)&xbuf[grp][PAR][0][l * 8];                 \
    const s16x8 a1 = *(const s16x8*)&xbuf[grp][PAR][1][l * 8];                 \
    _Pragma("unroll")                                                          \
    for (int g = 0; g < 3; ++g) {                                              \
      f32x4 zz = {0.f, 0.f, 0.f, 0.f};                                         \
      zz    = __builtin_amdgcn_mfma_f32_16x16x32_bf16(a2, breg[g][2], zz, 0,0,0);\
      hi[g] = __builtin_amdgcn_mfma_f32_16x16x32_bf16(a3, breg[g][3], zz, 0,0,0);\
      f32x4 yy = {0.f, 0.f, 0.f, 0.f};                                         \
      yy    = __builtin_amdgcn_mfma_f32_16x16x32_bf16(a0, breg[g][0], yy, 0,0,0);\
      lo[g] = __builtin_amdgcn_mfma_f32_16x16x32_bf16(a1, breg[g][1], yy, 0,0,0);\
    }                                                                          \
  }

#define GATE_STAGE(S, CUR)                                                     \
  {                                                                            \
    const int PW = ((S) + 1) & 1;                                              \
    {                                                                          \
      s16x4 pk;                                                                \
      pk[0] = (short)f2bf(CUR[0]); pk[1] = (short)f2bf(CUR[1]);                \
      pk[2] = (short)f2bf(CUR[2]); pk[3] = (short)f2bf(CUR[3]);                \
      *(s16x4*)(PW ? xd1 : xd0) = pk;                                          \
    }                                                                          \
    _Pragma("unroll")                                                          \
    for (int r = 0; r < 4; ++r) {                                              \
      float hv = (r == 0) ? h0 : (r == 1) ? h1 : (r == 2) ? h2 : h3;           \
      const float zs = lo[0][r] + hi[0][r] + bz;                               \
      const float rs = lo[1][r] + hi[1][r] + br;                               \
      const float z  = __builtin_amdgcn_rcpf(1.f + __expf(-zs));               \
      const float rr = __builtin_amdgcn_rcpf(1.f + __expf(-rs));               \
      const float ar = lo[2][r] + bh0 + rr * (hi[2][r] + bh1);                 \
      const float e  = __expf(2.f * ar);                                       \
      const float hh = 1.f - 2.f * __builtin_amdgcn_rcpf(1.f + e);             \
      hv = hh + z * (hv - hh);                                                 \
      if (r == 0) h0 = hv; else if (r == 1) h1 = hv;                           \
      else if (r == 2) h2 = hv; else h3 = hv;                                  \
      hbuf[grp][PW][u >> 5]                                                    \
          [(((u & 31) >> 3) * 16 + lhi * 4 + r) * 8 + (u & 7)] = f2bf(hv);     \
    }                                                                          \
  }

#define ITER(T, CUR, NXT, SKIPB)                                               \
  {                                                                            \
    if (grp == 0) { MFMA_STAGE(T, NXT) }                                       \
    else if (!(SKIPB)) { GATE_STAGE((T) - 1, CUR) }                            \
    RAWBAR();                                                                  \
    if (grp == 0) { GATE_STAGE(T, CUR) }                                       \
    else { MFMA_STAGE(T, NXT) }                                                \
    RAWBAR();                                                                  \
  }

  for (int t = 0; t < TS; t += 8) {
    ITER(t + 0, R0, S0, t == 0)
    ITER(t + 1, R1, S1, 0)
    ITER(t + 2, R2, S2, 0)
    ITER(t + 3, R3, S3, 0)
    ITER(t + 4, S0, R0, 0)
    ITER(t + 5, S1, R1, 0)
    ITER(t + 6, S2, R2, 0)
    ITER(t + 7, S3, R3, 0)
  }
#undef ITER
#undef GATE_STAGE
#undef MFMA_STAGE

  // B still owes gates(255) (reg-only; h-exchange no longer needed)
  if (grp) {
    #pragma unroll
    for (int r = 0; r < 4; ++r) {
      float hv = (r == 0) ? h0 : (r == 1) ? h1 : (r == 2) ? h2 : h3;
      const float zs = lo[0][r] + hi[0][r] + bz;
      const float rs = lo[1][r] + hi[1][r] + br;
      const float z  = __builtin_amdgcn_rcpf(1.f + __expf(-zs));
      const float rr = __builtin_amdgcn_rcpf(1.f + __expf(-rs));
      const float ar = lo[2][r] + bh0 + rr * (hi[2][r] + bh1);
      const float e  = __expf(2.f * ar);
      const float hh = 1.f - 2.f * __builtin_amdgcn_rcpf(1.f + e);
      hv = hh + z * (hv - hh);
      if (r == 0) h0 = hv; else if (r == 1) h1 = hv;
      else if (r == 2) h2 = hv; else h3 = hv;
    }
  }

  // epilogue: out[row] = sum_u h[row][u]*Wd[u] + bd (per group)
  const float Wdv = (u < 50) ? Wd[u] : 0.f;
  float p0 = h0 * Wdv, p1 = h1 * Wdv, p2 = h2 * Wdv, p3 = h3 * Wdv;
  #pragma unroll
  for (int m = 1; m < 16; m <<= 1) {
    p0 += __shfl_xor(p0, m);
    p1 += __shfl_xor(p1, m);
    p2 += __shfl_xor(p2, m);
    p3 += __shfl_xor(p3, m);
  }
  if (llo == 0) {
    red[grp][wg][lhi * 4 + 0] = p0;
    red[grp][wg][lhi * 4 + 1] = p1;
    red[grp][wg][lhi * 4 + 2] = p2;
    red[grp][wg][lhi * 4 + 3] = p3;
  }
  __syncthreads();
  if (tid < 32) {
    const int g = tid >> 4, r = tid & 15;
    out[(blockIdx.x << 5) + tid] =
        red[g][0][r] + red[g][1][r] + red[g][2][r] + red[g][3][r] + bdp[0];
  }
}

extern "C" void kernel_launch(void* const* d_in, const int* in_sizes, int n_in,
                              void* d_out, int out_size, void* d_ws, size_t ws_size,
                              hipStream_t stream) {
  const float* x   = (const float*)d_in[0];
  const float* W   = (const float*)d_in[1];
  const float* U   = (const float*)d_in[2];
  const float* b   = (const float*)d_in[3];
  const float* Wd  = (const float*)d_in[4];
  const float* bdp = (const float*)d_in[5];
  float* out = (float*)d_out;
  gru_fused<<<dim3(256), dim3(512), 0, stream>>>(x, W, U, b, Wd, bdp, out);
}

// Round 8
// 798.088 us; speedup vs baseline: 1.0216x; 1.0216x over previous
//
#include <hip/hip_runtime.h>
#include <hip/hip_bf16.h>

// GRU (reset_after) fused, MI355X gfx950. B=8192, T=256, F=64, H=50.
// Round-6 skeleton (512 blocks x 256 thr, 16 rows, 4 waves, gate-blocked B,
// 1 raw barrier/step) + : lo-hoist (x-part MFMAs for step T+1 run during
// step T, only the h-part is on the post-barrier critical path), exp2
// scale-folding (B cols z/r pre-scaled by -log2e, h by 2log2e; biases in
// MFMA C-init => bare v_exp_f32, no argument muls), v_cvt_pk_bf16_f32.

typedef __attribute__((ext_vector_type(8))) short s16x8;
typedef __attribute__((ext_vector_type(4))) float f32x4;

#define TS 256

__device__ __forceinline__ unsigned short f2bf(float f) {
  unsigned int v = __builtin_bit_cast(unsigned int, f);
  v += 0x7FFFu + ((v >> 16) & 1u);
  return (unsigned short)(v >> 16);
}
__device__ __forceinline__ unsigned int cvtpk(float a, float b) {
  unsigned int r;
  asm("v_cvt_pk_bf16_f32 %0, %1, %2" : "=v"(r) : "v"(a), "v"(b));
  return r;
}
__device__ __forceinline__ float rcpf(float a) {
  return __builtin_amdgcn_rcpf(a);
}

// LDS-visibility barrier WITHOUT vmcnt drain: global prefetches stay in flight.
#define RAWBAR()                                                \
  do {                                                          \
    asm volatile("s_waitcnt lgkmcnt(0)" ::: "memory");          \
    __builtin_amdgcn_sched_barrier(0);                          \
    __builtin_amdgcn_s_barrier();                               \
  } while (0)

__global__ __launch_bounds__(256, 2) void gru_fused(
    const float* __restrict__ x,  const float* __restrict__ W,
    const float* __restrict__ U,  const float* __restrict__ b,
    const float* __restrict__ Wd, const float* __restrict__ bdp,
    float* __restrict__ out)
{
  __shared__ __align__(16) unsigned short xbuf[2][2][512]; // [par][kchunk]
  __shared__ __align__(16) unsigned short hbuf[2][2][512];
  __shared__ float red[4][16];

  const int tid = threadIdx.x;
  const int l   = tid & 63;
  const int w   = tid >> 6;
  const int lhi = l >> 4, llo = l & 15;
  const int row0 = blockIdx.x << 4;
  const int u = (w << 4) + llo;            // hidden unit (pad >= 50)

  // h(t=-1) = 0 in hbuf par 0 (1024 shorts = 256 u64)
  ((unsigned long long*)hbuf)[tid] = 0ULL;

  const float sZR = -1.44269504088896f;    // -log2(e)
  const float sH  =  2.88539008177793f;    //  2*log2(e)
  float bzS = 0.f, brS = 0.f, bh0S = 0.f, bh1S = 0.f;
  if (u < 50) {
    bzS  = sZR * (b[u]      + b[150 + u]);
    brS  = sZR * (b[50 + u] + b[200 + u]);
    bh0S = sH * b[100 + u];
    bh1S = sH * b[250 + u];
  }

  // B fragments, gate-blocked cols (g: 0=z,1=r,2=h -> src col g*50+u),
  // pre-scaled so gate pre-activations are exp2 arguments directly.
  s16x8 breg[3][4];
  #pragma unroll
  for (int g = 0; g < 3; ++g) {
    const float sc = (g < 2) ? sZR : sH;
    #pragma unroll
    for (int kc = 0; kc < 4; ++kc) {
      s16x8 f;
      #pragma unroll
      for (int i = 0; i < 8; ++i) {
        const int k = kc * 32 + lhi * 8 + i;
        float v = 0.f;
        if (u < 50 && k < 114)
          v = (k < 64) ? W[k * 150 + g * 50 + u]
                       : U[(k - 64) * 150 + g * 50 + u];
        f[i] = (short)f2bf(v * sc);
      }
      breg[g][kc] = f;
    }
  }

  // x staging slot: thread covers 4 f32 -> 4 bf16 of the A-frag (8B).
  const int sc    = tid >> 7;
  const int sla   = (tid >> 1) & 63;
  const int shalf = tid & 1;
  const float* xp = x + (long)(row0 + (sla & 15)) * (TS * 64)
                      + sc * 32 + (sla >> 4) * 8 + shalf * 4;
  unsigned long long* const xd0 =
      (unsigned long long*)&xbuf[0][sc][sla * 8 + shalf * 4];
  unsigned long long* const xd1 =
      (unsigned long long*)&xbuf[1][sc][sla * 8 + shalf * 4];

  // h-store base (per-r offset = r*8 shorts; par offset = 1024 shorts)
  unsigned short* const hst =
      &hbuf[0][u >> 5][(((u & 31) >> 3) * 16 + lhi * 4) * 8 + (u & 7)];

  // ---- prologue: stage x(0)->par0, x(1)->par1; ring x(2..5) ----
  {
    const f32x4 t0 = *(const f32x4*)xp;
    *xd0 = ((unsigned long long)cvtpk(t0[2], t0[3]) << 32) | cvtpk(t0[0], t0[1]);
    const f32x4 t1 = *(const f32x4*)(xp + 64);
    *xd1 = ((unsigned long long)cvtpk(t1[2], t1[3]) << 32) | cvtpk(t1[0], t1[1]);
  }
  f32x4 X0, X1, X2, X3, X4, X5, X6, X7;
  X2 = *(const f32x4*)(xp + 2 * 64);
  X3 = *(const f32x4*)(xp + 3 * 64);
  X4 = *(const f32x4*)(xp + 4 * 64);
  X5 = *(const f32x4*)(xp + 5 * 64);
  __syncthreads();

  // lo_cur = x(0)*W (+ biases in C-init)
  f32x4 LA0 = {bzS, bzS, bzS, bzS}, LA1 = {brS, brS, brS, brS},
        LA2 = {bh0S, bh0S, bh0S, bh0S}, LB0, LB1, LB2;
  {
    const s16x8 a0 = *(const s16x8*)&xbuf[0][0][l * 8];
    const s16x8 a1 = *(const s16x8*)&xbuf[0][1][l * 8];
    LA0 = __builtin_amdgcn_mfma_f32_16x16x32_bf16(a0, breg[0][0], LA0, 0,0,0);
    LA0 = __builtin_amdgcn_mfma_f32_16x16x32_bf16(a1, breg[0][1], LA0, 0,0,0);
    LA1 = __builtin_amdgcn_mfma_f32_16x16x32_bf16(a0, breg[1][0], LA1, 0,0,0);
    LA1 = __builtin_amdgcn_mfma_f32_16x16x32_bf16(a1, breg[1][1], LA1, 0,0,0);
    LA2 = __builtin_amdgcn_mfma_f32_16x16x32_bf16(a0, breg[2][0], LA2, 0,0,0);
    LA2 = __builtin_amdgcn_mfma_f32_16x16x32_bf16(a1, breg[2][1], LA2, 0,0,0);
  }
  __syncthreads();  // protect xbuf[0] / hbuf[0] from step-0 overwrites

  float h0 = 0.f, h1 = 0.f, h2 = 0.f, h3 = 0.f;

// Step T (computes h(T)): consume ring XC=x(T+2)->xbuf[T&1]; load x(T+6)->XL;
// hi = h(T-1)*U from hbuf[T&1]; lo_next = x(T+1)*W from xbuf[(T+1)&1];
// gates from (LC, hi); h(T) -> hbuf[(T+1)&1]. One raw barrier.
#define STEP(T, XC, XL, C0, C1, C2, N0, N1, N2)                                \
  {                                                                            \
    const int tl = ((T) + 6 > TS - 1) ? (TS - 1) : ((T) + 6);                  \
    XL = *(const f32x4*)(xp + (long)tl * 64);                                  \
    const int PAR = (T) & 1;                                                   \
    const s16x8 a2 = *(const s16x8*)&hbuf[PAR][0][l * 8];                      \
    const s16x8 a3 = *(const s16x8*)&hbuf[PAR][1][l * 8];                      \
    f32x4 g0 = {0.f, 0.f, 0.f, 0.f}, g1 = {0.f, 0.f, 0.f, 0.f};               \
    f32x4 g2 = {bh1S, bh1S, bh1S, bh1S};                                       \
    g0 = __builtin_amdgcn_mfma_f32_16x16x32_bf16(a2, breg[0][2], g0, 0,0,0);   \
    g0 = __builtin_amdgcn_mfma_f32_16x16x32_bf16(a3, breg[0][3], g0, 0,0,0);   \
    g1 = __builtin_amdgcn_mfma_f32_16x16x32_bf16(a2, breg[1][2], g1, 0,0,0);   \
    g1 = __builtin_amdgcn_mfma_f32_16x16x32_bf16(a3, breg[1][3], g1, 0,0,0);   \
    g2 = __builtin_amdgcn_mfma_f32_16x16x32_bf16(a2, breg[2][2], g2, 0,0,0);   \
    g2 = __builtin_amdgcn_mfma_f32_16x16x32_bf16(a3, breg[2][3], g2, 0,0,0);   \
    const s16x8 a0 = *(const s16x8*)&xbuf[PAR ^ 1][0][l * 8];                  \
    const s16x8 a1 = *(const s16x8*)&xbuf[PAR ^ 1][1][l * 8];                  \
    N0 = (f32x4){bzS, bzS, bzS, bzS};                                          \
    N1 = (f32x4){brS, brS, brS, brS};                                          \
    N2 = (f32x4){bh0S, bh0S, bh0S, bh0S};                                      \
    N0 = __builtin_amdgcn_mfma_f32_16x16x32_bf16(a0, breg[0][0], N0, 0,0,0);   \
    N0 = __builtin_amdgcn_mfma_f32_16x16x32_bf16(a1, breg[0][1], N0, 0,0,0);   \
    N1 = __builtin_amdgcn_mfma_f32_16x16x32_bf16(a0, breg[1][0], N1, 0,0,0);   \
    N1 = __builtin_amdgcn_mfma_f32_16x16x32_bf16(a1, breg[1][1], N1, 0,0,0);   \
    N2 = __builtin_amdgcn_mfma_f32_16x16x32_bf16(a0, breg[2][0], N2, 0,0,0);   \
    N2 = __builtin_amdgcn_mfma_f32_16x16x32_bf16(a1, breg[2][1], N2, 0,0,0);   \
    *(PAR ? xd1 : xd0) =                                                       \
        ((unsigned long long)cvtpk(XC[2], XC[3]) << 32) | cvtpk(XC[0], XC[1]); \
    _Pragma("unroll")                                                          \
    for (int r = 0; r < 4; ++r) {                                              \
      float hv = (r == 0) ? h0 : (r == 1) ? h1 : (r == 2) ? h2 : h3;           \
      const float z  = rcpf(1.f + exp2f(C0[r] + g0[r]));                       \
      const float rr = rcpf(1.f + exp2f(C1[r] + g1[r]));                       \
      const float q  = rcpf(1.f + exp2f(fmaf(rr, g2[r], C2[r])));              \
      const float hh = fmaf(-2.f, q, 1.f);                                     \
      hv = fmaf(z, hv - hh, hh);                                               \
      if (r == 0) h0 = hv; else if (r == 1) h1 = hv;                           \
      else if (r == 2) h2 = hv; else h3 = hv;                                  \
      hst[(PAR ^ 1) * 1024 + r * 8] = (unsigned short)cvtpk(hv, 0.f);          \
    }                                                                          \
    RAWBAR();                                                                  \
  }

  for (int t = 0; t < TS; t += 8) {
    STEP(t + 0, X2, X6, LA0, LA1, LA2, LB0, LB1, LB2)
    STEP(t + 1, X3, X7, LB0, LB1, LB2, LA0, LA1, LA2)
    STEP(t + 2, X4, X0, LA0, LA1, LA2, LB0, LB1, LB2)
    STEP(t + 3, X5, X1, LB0, LB1, LB2, LA0, LA1, LA2)
    STEP(t + 4, X6, X2, LA0, LA1, LA2, LB0, LB1, LB2)
    STEP(t + 5, X7, X3, LB0, LB1, LB2, LA0, LA1, LA2)
    STEP(t + 6, X0, X4, LA0, LA1, LA2, LB0, LB1, LB2)
    STEP(t + 7, X1, X5, LB0, LB1, LB2, LA0, LA1, LA2)
  }
#undef STEP

  // epilogue: out[row] = sum_u h[row][u]*Wd[u] + bd
  const float Wdv = (u < 50) ? Wd[u] : 0.f;
  float p0 = h0 * Wdv, p1 = h1 * Wdv, p2 = h2 * Wdv, p3 = h3 * Wdv;
  #pragma unroll
  for (int m = 1; m < 16; m <<= 1) {
    p0 += __shfl_xor(p0, m);
    p1 += __shfl_xor(p1, m);
    p2 += __shfl_xor(p2, m);
    p3 += __shfl_xor(p3, m);
  }
  if (llo == 0) {
    red[w][lhi * 4 + 0] = p0;
    red[w][lhi * 4 + 1] = p1;
    red[w][lhi * 4 + 2] = p2;
    red[w][lhi * 4 + 3] = p3;
  }
  __syncthreads();
  if (tid < 16)
    out[row0 + tid] =
        red[0][tid] + red[1][tid] + red[2][tid] + red[3][tid] + bdp[0];
}

extern "C" void kernel_launch(void* const* d_in, const int* in_sizes, int n_in,
                              void* d_out, int out_size, void* d_ws, size_t ws_size,
                              hipStream_t stream) {
  const float* x   = (const float*)d_in[0];
  const float* W   = (const float*)d_in[1];
  const float* U   = (const float*)d_in[2];
  const float* b   = (const float*)d_in[3];
  const float* Wd  = (const float*)d_in[4];
  const float* bdp = (const float*)d_in[5];
  float* out = (float*)d_out;
  gru_fused<<<dim3(512), dim3(256), 0, stream>>>(x, W, U, b, Wd, bdp, out);
}